// Round 12
// baseline (41.941 us; speedup 1.0000x reference)
//
#include <hip/hip_runtime.h>
#include <hip/hip_bf16.h>
#include <cmath>

// GraphAttention: out = elu((softmax(mask_diag(lrelu(si+sj'))) + I) @ h), h = x@W^T + b
// B=8 N=2048 IN=256 H=128, ALPHA=0.2. adj_identity is broadcast eye(N).
//
// R12 = R11 rewritten for code hygiene (no LDS union, no pipelined macro):
// K1 writes hTt FRAGMENT-ORDERED [b][jt][seg=wk*4+g][col][8j]; K3 loads MFMA
// B-fragments directly global->reg (XCD-L2-resident), barrier-free j-loop,
// rotating 2-deep register prefetch, 3-round LDS pair reduction (32KB xch).
// w_ij = max(e1_i*f1_j, e2_i*f2_j) (exact lrelu identity); z via ones-MFMA;
// diagonal subtracted in epilogue; "+I" = residual +h_i (bf16 from hTt).

#define ALPHA 0.2f
#define NN 2048
#define NIN 256
#define NH 128

typedef __attribute__((ext_vector_type(8))) short short8;
typedef __attribute__((ext_vector_type(4))) float f32x4;

__device__ __forceinline__ unsigned int pk2(float a, float b) {
    unsigned int r;
    asm("v_cvt_pk_bf16_f32 %0, %1, %2" : "=v"(r) : "v"(a), "v"(b));
    return r;   // low16 = bf16(a), high16 = bf16(b), RNE
}

// ---------------------------------------------------------------------------
// K1: h = x @ W^T + b (bf16 MFMA, fp32 accum). Writes hTt bf16 fragment-
// ordered [b][jt][seg][col][8], si/sj. Grid 256 x 256thr.
// ---------------------------------------------------------------------------
__global__ __launch_bounds__(256) void k1_h(
    const float* __restrict__ x, const float* __restrict__ Wm,
    const float* __restrict__ bias, const float* __restrict__ av,
    float* __restrict__ si, float* __restrict__ sj,
    unsigned short* __restrict__ hTt)
{
    __shared__ __align__(16) unsigned short xls[64 * 264];
    __shared__ __align__(16) unsigned short Wls[128 * 264];
    __shared__ float a1l[128], a2l[128], bl[128];

    const int t = threadIdx.x;
    const int r0 = blockIdx.x * 64;

    for (int p = 0; p < 16; ++p) {
        int idx = p * 256 + t;
        int row = idx >> 6, kq = idx & 63;
        f32x4 v = *(const f32x4*)(x + (size_t)(r0 + row) * NIN + kq * 4);
        *(uint2*)(&xls[row * 264 + kq * 4]) = make_uint2(pk2(v[0], v[1]), pk2(v[2], v[3]));
    }
    for (int p = 0; p < 32; ++p) {
        int idx = p * 256 + t;
        int row = idx >> 6, kq = idx & 63;
        f32x4 v = *(const f32x4*)(Wm + (size_t)row * NIN + kq * 4);
        *(uint2*)(&Wls[row * 264 + kq * 4]) = make_uint2(pk2(v[0], v[1]), pk2(v[2], v[3]));
    }
    if (t < 128) { a1l[t] = av[t]; a2l[t] = av[128 + t]; bl[t] = bias[t]; }
    __syncthreads();

    const int w = t >> 6, l = t & 63, la = l & 15, g = l >> 4;

    f32x4 acc[8];
#pragma unroll
    for (int n = 0; n < 8; ++n) acc[n] = (f32x4){0.f, 0.f, 0.f, 0.f};

#pragma unroll
    for (int ks = 0; ks < 8; ++ks) {
        short8 af = *(const short8*)(&xls[(w * 16 + la) * 264 + ks * 32 + g * 8]);
#pragma unroll
        for (int n = 0; n < 8; ++n) {
            short8 bfr = *(const short8*)(&Wls[(n * 16 + la) * 264 + ks * 32 + g * 8]);
            acc[n] = __builtin_amdgcn_mfma_f32_16x16x32_bf16(af, bfr, acc[n], 0, 0, 0);
        }
    }

    float s1[4] = {0.f, 0.f, 0.f, 0.f}, s2[4] = {0.f, 0.f, 0.f, 0.f};
#pragma unroll
    for (int n = 0; n < 8; ++n) {
        int col = n * 16 + la;
#pragma unroll
        for (int r = 0; r < 4; ++r) {
            float v = acc[n][r] + bl[col];
            acc[n][r] = v;
            s1[r] += v * a1l[col];
            s2[r] += v * a2l[col];
        }
    }
#pragma unroll
    for (int r = 0; r < 4; ++r) {
#pragma unroll
        for (int m = 1; m < 16; m <<= 1) {
            s1[r] += __shfl_xor(s1[r], m, 64);
            s2[r] += __shfl_xor(s2[r], m, 64);
        }
    }
    if (la == 0) {
#pragma unroll
        for (int r = 0; r < 4; ++r) {
            int row = w * 16 + g * 4 + r;
            si[r0 + row] = s1[r];
            sj[r0 + row] = s2[r];
        }
    }

    // transpose-stage h bf16 -> oT[col][row(+72 pad)]
    __syncthreads();
    unsigned short* oT = xls;   // reuse as [128 col][72]
#pragma unroll
    for (int n = 0; n < 8; ++n) {
        int col = n * 16 + la;
        int row0 = w * 16 + g * 4;
        *(uint2*)(&oT[col * 72 + row0]) =
            make_uint2(pk2(acc[n][0], acc[n][1]), pk2(acc[n][2], acc[n][3]));
    }
    __syncthreads();
    // fragment-ordered store: chunk q = seg*128 + col holds shorts [q*8..q*8+7]
    const int b = r0 >> 11, jt = (r0 & (NN - 1)) >> 6;
    unsigned short* dst = hTt + ((size_t)(b * 32 + jt)) * 8192;
    for (int p = 0; p < 4; ++p) {
        int q = p * 256 + t;              // 0..1023
        int col = q & 127, seg = q >> 7;  // j = seg*8+u
        uint4 v = *(const uint4*)(&oT[col * 72 + seg * 8]);
        *(uint4*)(dst + q * 8) = v;
    }
}

// ---------------------------------------------------------------------------
// K3: fused stats + flash P@h, barrier-free j-loop. Grid 256 (bb=bid&7 XCD
// pin, grp=bid>>3: 64 i-rows), 512 thr; waves: wcg(2) x dup(2) x wk(2).
// B-frags global->reg, rotating 2-deep prefetch. z via ones-MFMA. 3-round
// 32KB xch reduction of the (dup,wk) partials; dw==0 epilogue. LDS 49KB.
// ---------------------------------------------------------------------------
__global__ __launch_bounds__(512) void k3_attn(
    const unsigned short* __restrict__ hTt,
    const float* __restrict__ si, const float* __restrict__ sj,
    float* __restrict__ out)
{
    __shared__ __align__(16) float f1l[NN];      // 8KB  e^{sj}
    __shared__ __align__(16) float f2l[NN];      // 8KB  e^{a*sj}
    __shared__ __align__(16) float xch[64][128]; // 32KB reduction buffer
    __shared__ float Zl[4][64];
    __shared__ float mr1[8], mr2[8];

    const int t = threadIdx.x;
    const int bb = blockIdx.x & 7;       // batch == XCD pin
    const int grp = blockIdx.x >> 3;     // 0..31
    const int i0 = grp * 64;
    const int w = t >> 6, l = t & 63;
    const int wcg = w >> 2;         // col group (64 cols)
    const int dup = (w >> 1) & 1;   // jt half (tiles dup*16..+15)
    const int wk  = w & 1;          // k half (32 j per 64-tile)
    const int la = l & 15, g = l >> 4;
    const int dw = dup * 2 + wk;    // 0..3

    const unsigned short* tb = hTt + (size_t)bb * (32 * 8192);
    // B-fragment base: element (col=wcg*64+la, j=(wk*4+g)*8+u) of a tile
    const unsigned short* bp = tb + (size_t)dup * (16 * 8192)
                             + ((wk * 4 + g) * 128 + wcg * 64 + la) * 8;

    // preload tiles dup*16 and dup*16+1 (latency hides under stats phase)
    short8 Pc[4], Pn[4];
#pragma unroll
    for (int n = 0; n < 4; ++n) Pc[n] = *(const short8*)(bp + n * 128);
#pragma unroll
    for (int n = 0; n < 4; ++n) Pn[n] = *(const short8*)(bp + 8192 + n * 128);

    // ---- stats: batch (max1,max2) of sj (direct global read) ----
    f32x4 vv = ((const f32x4*)(sj + bb * NN))[t];
    float m1, m2;
    {
        float hi0 = fmaxf(vv[0], vv[1]), lo0 = fminf(vv[0], vv[1]);
        float hi1 = fmaxf(vv[2], vv[3]), lo1 = fminf(vv[2], vv[3]);
        m1 = fmaxf(hi0, hi1);
        m2 = fmaxf(fminf(hi0, hi1), fmaxf(lo0, lo1));
    }
#pragma unroll
    for (int m = 1; m < 64; m <<= 1) {
        float o1 = __shfl_xor(m1, m, 64), o2 = __shfl_xor(m2, m, 64);
        float n1 = fmaxf(m1, o1);
        float n2 = fmaxf(fminf(m1, o1), fmaxf(m2, o2));
        m1 = n1; m2 = n2;
    }
    if (l == 0) { mr1[w] = m1; mr2[w] = m2; }
    __syncthreads();
    {
        float a1 = mr1[0], a2 = mr2[0];
#pragma unroll
        for (int wv2 = 1; wv2 < 8; ++wv2) {
            float b1 = mr1[wv2], b2 = mr2[wv2];
            float n1 = fmaxf(a1, b1), n2 = fmaxf(fminf(a1, b1), fmaxf(a2, b2));
            a1 = n1; a2 = n2;
        }
        m1 = a1; m2 = a2;
    }
    // exp tables (each thread owns 4 slots)
    {
        f32x4 e1t, e2t;
#pragma unroll
        for (int u = 0; u < 4; ++u) { e1t[u] = expf(vv[u]); e2t[u] = expf(ALPHA * vv[u]); }
        ((f32x4*)f1l)[t] = e1t;
        ((f32x4*)f2l)[t] = e2t;
    }

    // ---- per-row constants (4 rows/lane: rows i0 + fr*16 + la) ----
    float e1v[4], e2v[4], owv[4];
#pragma unroll
    for (int fr = 0; fr < 4; ++fr) {
        int gi = bb * NN + i0 + fr * 16 + la;
        float svi = si[gi], svj = sj[gi];
        float M = (svj == m1) ? m2 : m1;            // max_{k!=i} sj_k
        float sm = svi + M;
        float mm = sm > 0.f ? sm : ALPHA * sm;      // m_i = lrelu(si+M), guard only
        float a = expf(svi - mm), b2 = expf(ALPHA * svi - mm);
        e1v[fr] = a; e2v[fr] = b2;
        float owr = fmaxf(a * expf(svj), b2 * expf(ALPHA * svj)); // w_ii
        owv[fr] = __uint_as_float(pk2(owr, owr) << 16);           // bf16 round-trip
    }
    __syncthreads();   // exp tables visible before j-loop reads

    f32x4 acc[4][4], zac[4];
#pragma unroll
    for (int fr = 0; fr < 4; ++fr) {
        zac[fr] = (f32x4){0.f, 0.f, 0.f, 0.f};
#pragma unroll
        for (int n = 0; n < 4; ++n) acc[fr][n] = (f32x4){0.f, 0.f, 0.f, 0.f};
    }
    short8 ones;
#pragma unroll
    for (int u = 0; u < 8; ++u) ones[u] = (short)0x3F80;   // bf16 1.0

    const int jb0 = dup * 1024 + wk * 32 + g * 8;

    // ---- barrier-free j-loop: 16 tiles, rotating 2-deep prefetch ----
#pragma unroll 2
    for (int s = 0; s < 16; ++s) {
        const int jb = jb0 + s * 64;
        f32x4 F1a = *(const f32x4*)(f1l + jb);
        f32x4 F1b = *(const f32x4*)(f1l + jb + 4);
        f32x4 F2a = *(const f32x4*)(f2l + jb);
        f32x4 F2b = *(const f32x4*)(f2l + jb + 4);
#pragma unroll
        for (int fr = 0; fr < 4; ++fr) {
            const float e1 = e1v[fr], e2 = e2v[fr];
            float w0 = fmaxf(e1 * F1a[0], e2 * F2a[0]);
            float w1 = fmaxf(e1 * F1a[1], e2 * F2a[1]);
            float w2 = fmaxf(e1 * F1a[2], e2 * F2a[2]);
            float w3 = fmaxf(e1 * F1a[3], e2 * F2a[3]);
            float w4 = fmaxf(e1 * F1b[0], e2 * F2b[0]);
            float w5 = fmaxf(e1 * F1b[1], e2 * F2b[1]);
            float w6 = fmaxf(e1 * F1b[2], e2 * F2b[2]);
            float w7 = fmaxf(e1 * F1b[3], e2 * F2b[3]);
            union { unsigned int u4[4]; short8 s8; } cv;
            cv.u4[0] = pk2(w0, w1);
            cv.u4[1] = pk2(w2, w3);
            cv.u4[2] = pk2(w4, w5);
            cv.u4[3] = pk2(w6, w7);
            const short8 af = cv.s8;
            acc[fr][0] = __builtin_amdgcn_mfma_f32_16x16x32_bf16(af, Pc[0], acc[fr][0], 0, 0, 0);
            acc[fr][1] = __builtin_amdgcn_mfma_f32_16x16x32_bf16(af, Pc[1], acc[fr][1], 0, 0, 0);
            acc[fr][2] = __builtin_amdgcn_mfma_f32_16x16x32_bf16(af, Pc[2], acc[fr][2], 0, 0, 0);
            acc[fr][3] = __builtin_amdgcn_mfma_f32_16x16x32_bf16(af, Pc[3], acc[fr][3], 0, 0, 0);
            zac[fr]   = __builtin_amdgcn_mfma_f32_16x16x32_bf16(af, ones, zac[fr], 0, 0, 0);
        }
        // rotate and prefetch tile s+2
#pragma unroll
        for (int n = 0; n < 4; ++n) Pc[n] = Pn[n];
        if (s + 2 < 16) {
            const unsigned short* np = bp + (size_t)(s + 2) * 8192;
#pragma unroll
            for (int n = 0; n < 4; ++n) Pn[n] = *(const short8*)(np + n * 128);
        }
    }

    // ---- Z slots (per dw, from wcg==0 waves) ----
    if (wcg == 0 && la == 0) {
#pragma unroll
        for (int fr = 0; fr < 4; ++fr)
#pragma unroll
            for (int r = 0; r < 4; ++r)
                Zl[dw][fr * 16 + g * 4 + r] = zac[fr][r];
    }

    // ---- 3-round pair reduction of acc partials (dw=1,2,3 -> dw=0) ----
#pragma unroll
    for (int k = 1; k <= 3; ++k) {
        if (k > 1) __syncthreads();      // prior round's reads done before overwrite
        if (dw == k) {
#pragma unroll
            for (int fr = 0; fr < 4; ++fr)
#pragma unroll
                for (int n = 0; n < 4; ++n)
#pragma unroll
                    for (int r = 0; r < 4; ++r)
                        xch[fr * 16 + n * 4 + r][wcg * 64 + l] = acc[fr][n][r];
        }
        __syncthreads();
        if (dw == 0) {
#pragma unroll
            for (int fr = 0; fr < 4; ++fr)
#pragma unroll
                for (int n = 0; n < 4; ++n)
#pragma unroll
                    for (int r = 0; r < 4; ++r)
                        acc[fr][n][r] += xch[fr * 16 + n * 4 + r][wcg * 64 + l];
        }
    }

    // ---- epilogue (dw==0 waves): -own, normalize, +h residual, elu ----
    if (dw == 0) {
#pragma unroll
        for (int fr = 0; fr < 4; ++fr) {
#pragma unroll
            for (int n = 0; n < 4; ++n) {
                const int col = wcg * 64 + n * 16 + la;
#pragma unroll
                for (int r = 0; r < 4; ++r) {
                    const int row = fr * 16 + g * 4 + r;
                    const float Z = Zl[0][row] + Zl[1][row] + Zl[2][row] + Zl[3][row];
                    const int srcl = (g * 4 + r) | (l & 48);
                    const float owq = __shfl(owv[fr], srcl, 64);
                    const int gRow = i0 + row;
                    const int jt_r = gRow >> 6, jin = gRow & 63;
                    const float hv = __uint_as_float(
                        (unsigned int)tb[jt_r * 8192 + ((jin >> 3) * 128 + col) * 8 + (jin & 7)] << 16);
                    const float num = acc[fr][n][r] - owq * hv;
                    const float den = Z - owq;
                    float o = num / den + hv;
                    out[(size_t)(bb * NN + gRow) * NH + col] = o > 0.f ? o : expm1f(o);
                }
            }
        }
    }
}

// ---------------------------------------------------------------------------
extern "C" void kernel_launch(void* const* d_in, const int* in_sizes, int n_in,
                              void* d_out, int out_size, void* d_ws, size_t ws_size,
                              hipStream_t stream)
{
    const float* x    = (const float*)d_in[0];
    // d_in[1] = adj_identity (broadcast eye(N)) — handled analytically, never read.
    const float* Wm   = (const float*)d_in[2];
    const float* bias = (const float*)d_in[3];
    const float* av   = (const float*)d_in[4];
    float* out = (float*)d_out;

    float* wsf = (float*)d_ws;
    unsigned short* hTt = (unsigned short*)wsf;     // 8*32*8192 bf16 = 4MB
    float* si = wsf + 1048576;                      // 16384
    float* sj = wsf + 1064960;                      // 16384

    hipLaunchKernelGGL(k1_h,    dim3(256), dim3(256), 0, stream, x, Wm, bias, av, si, sj, hTt);
    hipLaunchKernelGGL(k3_attn, dim3(256), dim3(512), 0, stream, hTt, si, sj, out);
}